// Round 3
// baseline (5483.277 us; speedup 1.0000x reference)
//
#include <hip/hip_runtime.h>
#include <math.h>
#include <float.h>

#define EPSF 1e-8f
#define EPSD 1e-8
#define D_DIM 512
#define T_DIM 1024   // 2*D (r,i interleaved)
#define K_TOP 64
#define K_KEEP 128
#define NBIN 2048
#define CAND_MAX 2048

// ---------------- fp64 row magnitude from fp64 rows (q) ----------------
__global__ __launch_bounds__(256)
void rownorm_qd_kernel(const double* __restrict__ X, double* __restrict__ magd,
                       float* __restrict__ magf, int rows) {
  int r = blockIdx.x;
  if (r >= rows) return;
  int tid = threadIdx.x;
  const double* xr = X + (size_t)r * T_DIM;
  double s = 0.0;
  #pragma unroll
  for (int i = 0; i < 4; i++) { double v = xr[tid * 4 + i]; s += v * v; }
  for (int o = 32; o > 0; o >>= 1) s += __shfl_down(s, o, 64);
  __shared__ double red[4];
  if ((tid & 63) == 0) red[tid >> 6] = s;
  __syncthreads();
  if (tid == 0) {
    double m = sqrt(red[0] + red[1] + red[2] + red[3] + EPSD);
    magd[r] = m; magf[r] = (float)m;
  }
}

// ---------------- fp64 row magnitude from fp32 rows (keys) ----------------
__global__ __launch_bounds__(256)
void rownorm_kf_kernel(const float* __restrict__ X, double* __restrict__ magd,
                       float* __restrict__ magf, int rows) {
  int r = blockIdx.x;
  if (r >= rows) return;
  int tid = threadIdx.x;
  const float4* xr = (const float4*)(X + (size_t)r * T_DIM);
  float4 v = xr[tid];
  double s = (double)v.x * v.x + (double)v.y * v.y + (double)v.z * v.z + (double)v.w * v.w;
  for (int o = 32; o > 0; o >>= 1) s += __shfl_down(s, o, 64);
  __shared__ double red[4];
  if ((tid & 63) == 0) red[tid >> 6] = s;
  __syncthreads();
  if (tid == 0) {
    double m = sqrt(red[0] + red[1] + red[2] + red[3] + EPSD);
    magd[r] = m; magf[r] = (float)m;
  }
}

// ---------------- fp64-accumulate complex linear (query projection) ----------------
__global__ __launch_bounds__(256)
void cgemm_f64_kernel(const float* __restrict__ X,
                      const float* __restrict__ Wr, const float* __restrict__ Wi,
                      const float* __restrict__ br, const float* __restrict__ bi,
                      double* __restrict__ Yd, float* __restrict__ Yf, int M) {
  __shared__ float Ar[16][64], Ai[16][64], Br_[16][64], Bi_[16][64];
  int tid = threadIdx.x;
  int tx = tid & 15, ty = tid >> 4;
  int m0 = blockIdx.x * 64, n0 = blockIdx.y * 64;
  double accR[4][4] = {{0}}, accI[4][4] = {{0}};
  for (int k0 = 0; k0 < D_DIM; k0 += 16) {
    #pragma unroll
    for (int gi = 0; gi < 2; gi++) {
      int g = tid + gi * 256;
      int m = g >> 3, dg = g & 7;
      float4 v = *(const float4*)(X + (size_t)(m0 + m) * T_DIM + 2 * k0 + dg * 4);
      Ar[dg*2][m] = v.x; Ai[dg*2][m] = v.y; Ar[dg*2+1][m] = v.z; Ai[dg*2+1][m] = v.w;
    }
    {
      int j = tid >> 2, c = tid & 3;
      float4 vr = *(const float4*)(Wr + (size_t)(n0 + j) * D_DIM + k0 + c * 4);
      float4 vi = *(const float4*)(Wi + (size_t)(n0 + j) * D_DIM + k0 + c * 4);
      Br_[c*4+0][j] = vr.x; Br_[c*4+1][j] = vr.y; Br_[c*4+2][j] = vr.z; Br_[c*4+3][j] = vr.w;
      Bi_[c*4+0][j] = vi.x; Bi_[c*4+1][j] = vi.y; Bi_[c*4+2][j] = vi.z; Bi_[c*4+3][j] = vi.w;
    }
    __syncthreads();
    #pragma unroll
    for (int k = 0; k < 16; k++) {
      float arr[4], aii[4], wrr[4], wii[4];
      *(float4*)arr = *(const float4*)&Ar[k][ty*4];
      *(float4*)aii = *(const float4*)&Ai[k][ty*4];
      *(float4*)wrr = *(const float4*)&Br_[k][tx*4];
      *(float4*)wii = *(const float4*)&Bi_[k][tx*4];
      #pragma unroll
      for (int im = 0; im < 4; im++)
        #pragma unroll
        for (int jn = 0; jn < 4; jn++) {
          double ar = (double)arr[im], ai = (double)aii[im];
          double wr = (double)wrr[jn], wi = (double)wii[jn];
          accR[im][jn] += ar * wr - ai * wi;
          accI[im][jn] += ar * wi + ai * wr;
        }
    }
    __syncthreads();
  }
  #pragma unroll
  for (int im = 0; im < 4; im++) {
    int m = m0 + ty * 4 + im;
    #pragma unroll
    for (int jn = 0; jn < 4; jn++) {
      int j = n0 + tx * 4 + jn;
      double oR = accR[im][jn] + (double)br[j];
      double oI = accI[im][jn] + (double)bi[j];
      size_t base = (size_t)m * T_DIM + j * 2;
      Yd[base] = oR; Yd[base + 1] = oI;
      float2 f; f.x = (float)oR; f.y = (float)oI;
      *(float2*)(Yf + base) = f;
    }
  }
}

// ---------------- fp32 complex linear (output projection) ----------------
__global__ __launch_bounds__(256)
void cgemm_kernel(const float* __restrict__ X,
                  const float* __restrict__ Wr, const float* __restrict__ Wi,
                  const float* __restrict__ br, const float* __restrict__ bi,
                  float* __restrict__ Y, int M) {
  __shared__ float Ar[16][64], Ai[16][64], Br_[16][64], Bi_[16][64];
  int tid = threadIdx.x;
  int tx = tid & 15, ty = tid >> 4;
  int m0 = blockIdx.x * 64, n0 = blockIdx.y * 64;
  float accR[4][4] = {{0}}, accI[4][4] = {{0}};
  for (int k0 = 0; k0 < D_DIM; k0 += 16) {
    #pragma unroll
    for (int gi = 0; gi < 2; gi++) {
      int g = tid + gi * 256;
      int m = g >> 3, dg = g & 7;
      float4 v = *(const float4*)(X + (size_t)(m0 + m) * T_DIM + 2 * k0 + dg * 4);
      Ar[dg*2][m] = v.x; Ai[dg*2][m] = v.y; Ar[dg*2+1][m] = v.z; Ai[dg*2+1][m] = v.w;
    }
    {
      int j = tid >> 2, c = tid & 3;
      float4 vr = *(const float4*)(Wr + (size_t)(n0 + j) * D_DIM + k0 + c * 4);
      float4 vi = *(const float4*)(Wi + (size_t)(n0 + j) * D_DIM + k0 + c * 4);
      Br_[c*4+0][j] = vr.x; Br_[c*4+1][j] = vr.y; Br_[c*4+2][j] = vr.z; Br_[c*4+3][j] = vr.w;
      Bi_[c*4+0][j] = vi.x; Bi_[c*4+1][j] = vi.y; Bi_[c*4+2][j] = vi.z; Bi_[c*4+3][j] = vi.w;
    }
    __syncthreads();
    #pragma unroll
    for (int k = 0; k < 16; k++) {
      float arr[4], aii[4], wrr[4], wii[4];
      *(float4*)arr = *(const float4*)&Ar[k][ty*4];
      *(float4*)aii = *(const float4*)&Ai[k][ty*4];
      *(float4*)wrr = *(const float4*)&Br_[k][tx*4];
      *(float4*)wii = *(const float4*)&Bi_[k][tx*4];
      #pragma unroll
      for (int im = 0; im < 4; im++)
        #pragma unroll
        for (int jn = 0; jn < 4; jn++) {
          accR[im][jn] += arr[im] * wrr[jn] - aii[im] * wii[jn];
          accI[im][jn] += arr[im] * wii[jn] + aii[im] * wrr[jn];
        }
    }
    __syncthreads();
  }
  #pragma unroll
  for (int im = 0; im < 4; im++) {
    int m = m0 + ty * 4 + im;
    #pragma unroll
    for (int jn = 0; jn < 4; jn++) {
      int j = n0 + tx * 4 + jn;
      float2 o; o.x = accR[im][jn] + br[j]; o.y = accI[im][jn] + bi[j];
      *(float2*)(Y + (size_t)m * T_DIM + j * 2) = o;
    }
  }
}

// ---------------- fp32 coherence filter scores for a key chunk ----------------
__global__ __launch_bounds__(256)
void coh_kernel(const float* __restrict__ Q, const float* __restrict__ Kk,
                const float* __restrict__ qmag, const float* __restrict__ kmag,
                float* __restrict__ S, int n_off, int C) {
  __shared__ float At[16][128], Bt[16][128];
  int tid = threadIdx.x;
  int tx = tid & 15, ty = tid >> 4;
  int m0 = blockIdx.x * 128;
  int c0 = blockIdx.y * 128;
  int n0 = n_off + c0;
  float acc[8][8] = {{0}};
  for (int k0 = 0; k0 < T_DIM; k0 += 16) {
    #pragma unroll
    for (int gi = 0; gi < 2; gi++) {
      int g = tid + gi * 256;
      int r = g >> 2, c = g & 3;
      float4 va = *(const float4*)(Q + (size_t)(m0 + r) * T_DIM + k0 + c * 4);
      At[c*4+0][r] = va.x; At[c*4+1][r] = va.y; At[c*4+2][r] = va.z; At[c*4+3][r] = va.w;
      float4 vb = *(const float4*)(Kk + (size_t)(n0 + r) * T_DIM + k0 + c * 4);
      Bt[c*4+0][r] = vb.x; Bt[c*4+1][r] = vb.y; Bt[c*4+2][r] = vb.z; Bt[c*4+3][r] = vb.w;
    }
    __syncthreads();
    #pragma unroll
    for (int k = 0; k < 16; k++) {
      float a[8], b[8];
      *(float4*)&a[0] = *(const float4*)&At[k][ty*8];
      *(float4*)&a[4] = *(const float4*)&At[k][ty*8+4];
      *(float4*)&b[0] = *(const float4*)&Bt[k][tx*8];
      *(float4*)&b[4] = *(const float4*)&Bt[k][tx*8+4];
      #pragma unroll
      for (int im = 0; im < 8; im++)
        #pragma unroll
        for (int jn = 0; jn < 8; jn++)
          acc[im][jn] += a[im] * b[jn];
    }
    __syncthreads();
  }
  float qm[8], km[8];
  #pragma unroll
  for (int i = 0; i < 8; i++) { qm[i] = qmag[m0 + ty*8 + i]; km[i] = kmag[n0 + tx*8 + i]; }
  #pragma unroll
  for (int im = 0; im < 8; im++) {
    float outv[8];
    #pragma unroll
    for (int jn = 0; jn < 8; jn++) outv[jn] = acc[im][jn] / (qm[im] * km[jn] + EPSF);
    size_t base = (size_t)(m0 + ty*8 + im) * C + c0 + tx*8;
    *(float4*)(S + base)     = *(float4*)&outv[0];
    *(float4*)(S + base + 4) = *(float4*)&outv[4];
  }
}

// ---------------- exact per-chunk top-128 via histogram pivot select ----------------
// Monotonic key: u = f<0 ? ~bits : bits|0x80000000 (larger float -> larger u).
__global__ __launch_bounds__(256)
void select_kernel(const float* __restrict__ S, int C, int key_off,
                   int slot_off, int nslot,
                   float* __restrict__ cand_v, int* __restrict__ cand_i) {
  int q = blockIdx.x, tid = threadIdx.x;
  __shared__ unsigned hist[NBIN];
  __shared__ float bv[CAND_MAX];
  __shared__ int bi[CAND_MAX];
  __shared__ unsigned cnt_s, binB_s;
  for (int i = tid; i < NBIN; i += 256) hist[i] = 0;
  if (tid == 0) cnt_s = 0;
  __syncthreads();
  const float* row = S + (size_t)q * C;
  for (int i = tid; i < C; i += 256) {
    unsigned u = __float_as_uint(row[i]);
    u = (u & 0x80000000u) ? ~u : (u | 0x80000000u);
    atomicAdd(&hist[u >> 21], 1u);
  }
  __syncthreads();
  if (tid == 0) {
    unsigned acc = 0; unsigned B = 0;
    for (int b = NBIN - 1; b >= 0; b--) {
      acc += hist[b];
      if (acc >= (unsigned)K_KEEP) { B = (unsigned)b; break; }
    }
    binB_s = B;
  }
  __syncthreads();
  unsigned B = binB_s;
  for (int i = tid; i < C; i += 256) {
    float f = row[i];
    unsigned u = __float_as_uint(f);
    u = (u & 0x80000000u) ? ~u : (u | 0x80000000u);
    if ((u >> 21) >= B) {
      unsigned p = atomicAdd(&cnt_s, 1u);
      if (p < CAND_MAX) { bv[p] = f; bi[p] = key_off + i; }
    }
  }
  __syncthreads();
  int cnt = (int)min(cnt_s, (unsigned)CAND_MAX);
  int n = K_KEEP; while (n < cnt) n <<= 1;     // pow2, <= CAND_MAX
  for (int x = cnt + tid; x < n; x += 256) { bv[x] = -FLT_MAX; bi[x] = 0x7FFFFFFF; }
  // bitonic sort desc (value), tie: smaller index first
  for (int k = 2; k <= n; k <<= 1) {
    for (int j = k >> 1; j > 0; j >>= 1) {
      __syncthreads();
      for (int i = tid; i < n; i += 256) {
        int ixj = i ^ j;
        if (ixj > i) {
          float a = bv[i], b = bv[ixj];
          int ia = bi[i], ib = bi[ixj];
          bool a_worse = (a < b) || (a == b && ia > ib);
          bool up = ((i & k) == 0);
          if (up ? a_worse : !a_worse) {
            bv[i] = b; bv[ixj] = a; bi[i] = ib; bi[ixj] = ia;
          }
        }
      }
    }
  }
  __syncthreads();
  if (tid < K_KEEP) {
    cand_v[(size_t)q * nslot + slot_off + tid] = bv[tid];
    cand_i[(size_t)q * nslot + slot_off + tid] = bi[tid];
  }
}

// ---------------- merge per-chunk candidate lists -> global top-128 indices ----------------
__global__ __launch_bounds__(256)
void merge_kernel(const float* __restrict__ cand_v, const int* __restrict__ cand_i,
                  int nslot, int* __restrict__ topi) {
  int q = blockIdx.x, tid = threadIdx.x;
  __shared__ float bv[CAND_MAX];
  __shared__ int bi[CAND_MAX];
  int n = K_KEEP; while (n < nslot) n <<= 1;   // nslot = nchunks*128 (pow2) -> n == max(nslot,128)
  for (int i = tid; i < n; i += 256) {
    if (i < nslot) { bv[i] = cand_v[(size_t)q * nslot + i]; bi[i] = cand_i[(size_t)q * nslot + i]; }
    else { bv[i] = -FLT_MAX; bi[i] = 0x7FFFFFFF; }
  }
  for (int k = 2; k <= n; k <<= 1) {
    for (int j = k >> 1; j > 0; j >>= 1) {
      __syncthreads();
      for (int i = tid; i < n; i += 256) {
        int ixj = i ^ j;
        if (ixj > i) {
          float a = bv[i], b = bv[ixj];
          int ia = bi[i], ib = bi[ixj];
          bool a_worse = (a < b) || (a == b && ia > ib);
          bool up = ((i & k) == 0);
          if (up ? a_worse : !a_worse) {
            bv[i] = b; bv[ixj] = a; bi[i] = ib; bi[ixj] = ia;
          }
        }
      }
    }
  }
  __syncthreads();
  if (tid < K_KEEP) topi[q * K_KEEP + tid] = bi[tid];
}

// ---------------- fp64 exact rescore + top-64 + softmax + gather + phase_norm ----------------
__global__ __launch_bounds__(256)
void rescore_kernel(const int* __restrict__ topi,
                    const double* __restrict__ Qd,
                    const double* __restrict__ qmagd, const double* __restrict__ kmagd,
                    const float* __restrict__ Kk, const float* __restrict__ V,
                    const float* __restrict__ gamma,
                    float* __restrict__ XN) {
  int q = blockIdx.x, tid = threadIdx.x;
  __shared__ double qrow[T_DIM];
  __shared__ double cval[K_KEEP];
  __shared__ int cidx[K_KEEP];
  __shared__ float w[K_TOP];
  __shared__ int widx[K_TOP];
  __shared__ float red[4];
  for (int i = tid; i < T_DIM; i += 256) qrow[i] = Qd[(size_t)q * T_DIM + i];
  if (tid < K_KEEP) cidx[tid] = topi[q * K_KEEP + tid];
  __syncthreads();
  double qm = qmagd[q];
  int wv = tid >> 6, ln = tid & 63;
  for (int c = wv; c < K_KEEP; c += 4) {
    int key = cidx[c];
    const float* kr = Kk + (size_t)key * T_DIM;
    double s = 0.0;
    #pragma unroll
    for (int it = 0; it < 16; it++) {
      int t = ln + it * 64;
      s += (double)kr[t] * qrow[t];
    }
    for (int o = 32; o > 0; o >>= 1) s += __shfl_down(s, o, 64);
    if (ln == 0) cval[c] = s / (qm * kmagd[key] + EPSD);
  }
  __syncthreads();
  for (int k = 2; k <= K_KEEP; k <<= 1) {
    for (int j = k >> 1; j > 0; j >>= 1) {
      __syncthreads();
      if (tid < K_KEEP) {
        int i = tid, ixj = i ^ j;
        if (ixj > i) {
          double a = cval[i], b = cval[ixj];
          int ia = cidx[i], ib = cidx[ixj];
          bool a_worse = (a < b) || (a == b && ia > ib);
          bool up = ((i & k) == 0);
          if (up ? a_worse : !a_worse) {
            cval[i] = b; cval[ixj] = a; cidx[i] = ib; cidx[ixj] = ia;
          }
        }
      }
    }
  }
  __syncthreads();
  if (tid < 64) {
    double v = cval[tid];
    double m = cval[0];
    double e = exp(v - m);
    double s = e;
    for (int o = 32; o > 0; o >>= 1) s += __shfl_down(s, o, 64);
    s = __shfl(s, 0, 64);
    w[tid] = (float)(e / s);
    widx[tid] = cidx[tid];
  }
  __syncthreads();
  float4 acc = {0.f, 0.f, 0.f, 0.f};
  #pragma unroll 4
  for (int j2 = 0; j2 < 64; j2++) {
    float wj = w[j2];
    float4 v = *(const float4*)(V + (size_t)widx[j2] * T_DIM + tid * 4);
    acc.x += wj * v.x; acc.y += wj * v.y; acc.z += wj * v.z; acc.w += wj * v.w;
  }
  float ls = acc.x*acc.x + acc.y*acc.y + acc.z*acc.z + acc.w*acc.w;
  for (int o = 32; o > 0; o >>= 1) ls += __shfl_down(ls, o, 64);
  if ((tid & 63) == 0) red[tid >> 6] = ls;
  __syncthreads();
  float tot = red[0] + red[1] + red[2] + red[3];
  float rms = sqrtf(tot / (float)D_DIM + EPSF);
  float g0 = gamma[tid * 2] / rms, g1 = gamma[tid * 2 + 1] / rms;
  float4 o = { acc.x * g0, acc.y * g0, acc.z * g1, acc.w * g1 };
  *(float4*)(XN + (size_t)q * T_DIM + tid * 4) = o;
}

extern "C" void kernel_launch(void* const* d_in, const int* in_sizes, int n_in,
                              void* d_out, int out_size, void* d_ws, size_t ws_size,
                              hipStream_t stream) {
  const float* query  = (const float*)d_in[0];
  const float* keys   = (const float*)d_in[1];
  const float* values = (const float*)d_in[2];
  const float* Wq_r   = (const float*)d_in[3];
  const float* Wq_i   = (const float*)d_in[4];
  const float* bq_r   = (const float*)d_in[5];
  const float* bq_i   = (const float*)d_in[6];
  const float* Wo_r   = (const float*)d_in[7];
  const float* Wo_i   = (const float*)d_in[8];
  const float* bo_r   = (const float*)d_in[9];
  const float* bo_i   = (const float*)d_in[10];
  const float* gamma  = (const float*)d_in[11];
  float* out = (float*)d_out;

  int M = in_sizes[0] / T_DIM;   // 4096
  int N = in_sizes[1] / T_DIM;   // 32768

  char* ws = (char*)d_ws;
  size_t off = 0;
  double* qd    = (double*)(ws + off); off += (size_t)M * T_DIM * 8;
  float*  qf    = (float*) (ws + off); off += (size_t)M * T_DIM * 4;
  float*  xn    = (float*) (ws + off); off += (size_t)M * T_DIM * 4;
  double* qmagd = (double*)(ws + off); off += (size_t)M * 8;
  float*  qmagf = (float*) (ws + off); off += (size_t)M * 4;
  double* kmagd = (double*)(ws + off); off += (size_t)N * 8;
  float*  kmagf = (float*) (ws + off); off += (size_t)N * 4;
  int*    topi  = (int*)   (ws + off); off += (size_t)M * K_KEEP * 4;
  float*  candv = (float*) (ws + off); off += (size_t)M * CAND_MAX * 4;
  int*    candi = (int*)   (ws + off); off += (size_t)M * CAND_MAX * 4;
  float*  sc    = (float*) (ws + off);
  size_t remain = (ws_size > off) ? (ws_size - off) : 0;

  int C = 2048;
  for (int c = 32768; c >= 2048; c >>= 1) {
    if (c <= N && (size_t)M * c * 4 <= remain) { C = c; break; }
  }
  if (C > N) C = N;
  int nchunks = N / C;
  int nslot = nchunks * K_KEEP;   // <= 2048

  dim3 blk(256);
  cgemm_f64_kernel<<<dim3(M / 64, D_DIM / 64), blk, 0, stream>>>(query, Wq_r, Wq_i, bq_r, bq_i, qd, qf, M);
  rownorm_qd_kernel<<<dim3(M), blk, 0, stream>>>(qd, qmagd, qmagf, M);
  rownorm_kf_kernel<<<dim3(N), blk, 0, stream>>>(keys, kmagd, kmagf, N);
  for (int c = 0; c < nchunks; c++) {
    int noff = c * C;
    coh_kernel<<<dim3(M / 128, C / 128), blk, 0, stream>>>(qf, keys, qmagf, kmagf, sc, noff, C);
    select_kernel<<<dim3(M), blk, 0, stream>>>(sc, C, noff, c * K_KEEP, nslot, candv, candi);
  }
  merge_kernel<<<dim3(M), blk, 0, stream>>>(candv, candi, nslot, topi);
  rescore_kernel<<<dim3(M), blk, 0, stream>>>(topi, qd, qmagd, kmagd, keys, values, gamma, xn);
  cgemm_kernel<<<dim3(M / 64, D_DIM / 64), blk, 0, stream>>>(xn, Wo_r, Wo_i, bo_r, bo_i, out, M);
}

// Round 4
// 2571.025 us; speedup vs baseline: 2.1327x; 2.1327x over previous
//
#include <hip/hip_runtime.h>
#include <math.h>
#include <float.h>

#define EPSF 1e-8f
#define EPSD 1e-8
#define D_DIM 512
#define T_DIM 1024   // 2*D (r,i interleaved)
#define K_TOP 64
#define K_KEEP 128
#define NBIN 2048
#define CAND_MAX 2048

typedef __bf16 bf16_t;
typedef __bf16 bf16x8 __attribute__((ext_vector_type(8)));
typedef __bf16 bf16x4 __attribute__((ext_vector_type(4)));
typedef float f32x4 __attribute__((ext_vector_type(4)));

// ---------------- fp64 row magnitude + bf16 normalized copy (q, from fp64 rows) ----------------
__global__ __launch_bounds__(256)
void rownorm_convert_q_kernel(const double* __restrict__ X, double* __restrict__ magd,
                              bf16_t* __restrict__ Qn, int rows) {
  int r = blockIdx.x;
  if (r >= rows) return;
  int tid = threadIdx.x;
  const double* xr = X + (size_t)r * T_DIM;
  double v[4];
  double s = 0.0;
  #pragma unroll
  for (int i = 0; i < 4; i++) { v[i] = xr[tid * 4 + i]; s += v[i] * v[i]; }
  for (int o = 32; o > 0; o >>= 1) s += __shfl_down(s, o, 64);
  __shared__ double red[4];
  __shared__ double mag_s;
  if ((tid & 63) == 0) red[tid >> 6] = s;
  __syncthreads();
  if (tid == 0) {
    double m = sqrt(red[0] + red[1] + red[2] + red[3] + EPSD);
    magd[r] = m; mag_s = m;
  }
  __syncthreads();
  double inv = 1.0 / mag_s;
  bf16x4 o;
  #pragma unroll
  for (int i = 0; i < 4; i++) o[i] = (bf16_t)((float)(v[i] * inv));
  *(bf16x4*)(Qn + (size_t)r * T_DIM + tid * 4) = o;
}

// ---------------- fp64 row magnitude + bf16 normalized copy (keys, from fp32 rows) ----------------
__global__ __launch_bounds__(256)
void rownorm_convert_k_kernel(const float* __restrict__ X, double* __restrict__ magd,
                              bf16_t* __restrict__ Kn, int rows) {
  int r = blockIdx.x;
  if (r >= rows) return;
  int tid = threadIdx.x;
  float4 v = ((const float4*)(X + (size_t)r * T_DIM))[tid];
  double s = (double)v.x * v.x + (double)v.y * v.y + (double)v.z * v.z + (double)v.w * v.w;
  for (int o = 32; o > 0; o >>= 1) s += __shfl_down(s, o, 64);
  __shared__ double red[4];
  __shared__ float inv_s;
  if ((tid & 63) == 0) red[tid >> 6] = s;
  __syncthreads();
  if (tid == 0) {
    double m = sqrt(red[0] + red[1] + red[2] + red[3] + EPSD);
    magd[r] = m; inv_s = (float)(1.0 / m);
  }
  __syncthreads();
  float inv = inv_s;
  bf16x4 o;
  o[0] = (bf16_t)(v.x * inv); o[1] = (bf16_t)(v.y * inv);
  o[2] = (bf16_t)(v.z * inv); o[3] = (bf16_t)(v.w * inv);
  *(bf16x4*)(Kn + (size_t)r * T_DIM + tid * 4) = o;
}

// ---------------- fp64-accumulate complex linear (query projection) ----------------
__global__ __launch_bounds__(256)
void cgemm_f64_kernel(const float* __restrict__ X,
                      const float* __restrict__ Wr, const float* __restrict__ Wi,
                      const float* __restrict__ br, const float* __restrict__ bi,
                      double* __restrict__ Yd, int M) {
  __shared__ float Ar[16][64], Ai[16][64], Br_[16][64], Bi_[16][64];
  int tid = threadIdx.x;
  int tx = tid & 15, ty = tid >> 4;
  int m0 = blockIdx.x * 64, n0 = blockIdx.y * 64;
  double accR[4][4] = {{0}}, accI[4][4] = {{0}};
  for (int k0 = 0; k0 < D_DIM; k0 += 16) {
    #pragma unroll
    for (int gi = 0; gi < 2; gi++) {
      int g = tid + gi * 256;
      int m = g >> 3, dg = g & 7;
      float4 v = *(const float4*)(X + (size_t)(m0 + m) * T_DIM + 2 * k0 + dg * 4);
      Ar[dg*2][m] = v.x; Ai[dg*2][m] = v.y; Ar[dg*2+1][m] = v.z; Ai[dg*2+1][m] = v.w;
    }
    {
      int j = tid >> 2, c = tid & 3;
      float4 vr = *(const float4*)(Wr + (size_t)(n0 + j) * D_DIM + k0 + c * 4);
      float4 vi = *(const float4*)(Wi + (size_t)(n0 + j) * D_DIM + k0 + c * 4);
      Br_[c*4+0][j] = vr.x; Br_[c*4+1][j] = vr.y; Br_[c*4+2][j] = vr.z; Br_[c*4+3][j] = vr.w;
      Bi_[c*4+0][j] = vi.x; Bi_[c*4+1][j] = vi.y; Bi_[c*4+2][j] = vi.z; Bi_[c*4+3][j] = vi.w;
    }
    __syncthreads();
    #pragma unroll
    for (int k = 0; k < 16; k++) {
      float arr[4], aii[4], wrr[4], wii[4];
      *(float4*)arr = *(const float4*)&Ar[k][ty*4];
      *(float4*)aii = *(const float4*)&Ai[k][ty*4];
      *(float4*)wrr = *(const float4*)&Br_[k][tx*4];
      *(float4*)wii = *(const float4*)&Bi_[k][tx*4];
      #pragma unroll
      for (int im = 0; im < 4; im++)
        #pragma unroll
        for (int jn = 0; jn < 4; jn++) {
          double ar = (double)arr[im], ai = (double)aii[im];
          double wr = (double)wrr[jn], wi = (double)wii[jn];
          accR[im][jn] += ar * wr - ai * wi;
          accI[im][jn] += ar * wi + ai * wr;
        }
    }
    __syncthreads();
  }
  #pragma unroll
  for (int im = 0; im < 4; im++) {
    int m = m0 + ty * 4 + im;
    #pragma unroll
    for (int jn = 0; jn < 4; jn++) {
      int j = n0 + tx * 4 + jn;
      size_t base = (size_t)m * T_DIM + j * 2;
      Yd[base]     = accR[im][jn] + (double)br[j];
      Yd[base + 1] = accI[im][jn] + (double)bi[j];
    }
  }
}

// ---------------- fp32 complex linear (output projection) ----------------
__global__ __launch_bounds__(256)
void cgemm_kernel(const float* __restrict__ X,
                  const float* __restrict__ Wr, const float* __restrict__ Wi,
                  const float* __restrict__ br, const float* __restrict__ bi,
                  float* __restrict__ Y, int M) {
  __shared__ float Ar[16][64], Ai[16][64], Br_[16][64], Bi_[16][64];
  int tid = threadIdx.x;
  int tx = tid & 15, ty = tid >> 4;
  int m0 = blockIdx.x * 64, n0 = blockIdx.y * 64;
  float accR[4][4] = {{0}}, accI[4][4] = {{0}};
  for (int k0 = 0; k0 < D_DIM; k0 += 16) {
    #pragma unroll
    for (int gi = 0; gi < 2; gi++) {
      int g = tid + gi * 256;
      int m = g >> 3, dg = g & 7;
      float4 v = *(const float4*)(X + (size_t)(m0 + m) * T_DIM + 2 * k0 + dg * 4);
      Ar[dg*2][m] = v.x; Ai[dg*2][m] = v.y; Ar[dg*2+1][m] = v.z; Ai[dg*2+1][m] = v.w;
    }
    {
      int j = tid >> 2, c = tid & 3;
      float4 vr = *(const float4*)(Wr + (size_t)(n0 + j) * D_DIM + k0 + c * 4);
      float4 vi = *(const float4*)(Wi + (size_t)(n0 + j) * D_DIM + k0 + c * 4);
      Br_[c*4+0][j] = vr.x; Br_[c*4+1][j] = vr.y; Br_[c*4+2][j] = vr.z; Br_[c*4+3][j] = vr.w;
      Bi_[c*4+0][j] = vi.x; Bi_[c*4+1][j] = vi.y; Bi_[c*4+2][j] = vi.z; Bi_[c*4+3][j] = vi.w;
    }
    __syncthreads();
    #pragma unroll
    for (int k = 0; k < 16; k++) {
      float arr[4], aii[4], wrr[4], wii[4];
      *(float4*)arr = *(const float4*)&Ar[k][ty*4];
      *(float4*)aii = *(const float4*)&Ai[k][ty*4];
      *(float4*)wrr = *(const float4*)&Br_[k][tx*4];
      *(float4*)wii = *(const float4*)&Bi_[k][tx*4];
      #pragma unroll
      for (int im = 0; im < 4; im++)
        #pragma unroll
        for (int jn = 0; jn < 4; jn++) {
          accR[im][jn] += arr[im] * wrr[jn] - aii[im] * wii[jn];
          accI[im][jn] += arr[im] * wii[jn] + aii[im] * wrr[jn];
        }
    }
    __syncthreads();
  }
  #pragma unroll
  for (int im = 0; im < 4; im++) {
    int m = m0 + ty * 4 + im;
    #pragma unroll
    for (int jn = 0; jn < 4; jn++) {
      int j = n0 + tx * 4 + jn;
      float2 o; o.x = accR[im][jn] + br[j]; o.y = accI[im][jn] + bi[j];
      *(float2*)(Y + (size_t)m * T_DIM + j * 2) = o;
    }
  }
}

// ---------------- bf16 MFMA filter scores: S[m][c] = dot(Qn[m], Kn[n_off+c]) ----------------
// 128x128 tile, BK=32, 16x16x32 MFMA, global_load_lds width=16 (m97 structure).
__global__ __launch_bounds__(256)
void mfma_score_kernel(const bf16_t* __restrict__ Qn, const bf16_t* __restrict__ Kn,
                       float* __restrict__ S, int n_off, int C) {
  __shared__ bf16_t As[128 * 32];   // row-major [128][32], 64B/row
  __shared__ bf16_t Bs[128 * 32];
  int tid = threadIdx.x;
  int lane = tid & 63, wv = tid >> 6;
  int m0 = blockIdx.x * 128;
  int n0 = blockIdx.y * 128;                 // within chunk
  int wm = (wv & 1) * 64, wn = (wv >> 1) * 64;
  f32x4 acc[4][4] = {};
  const bf16_t* Ag = Qn + (size_t)m0 * T_DIM;
  const bf16_t* Bg = Kn + (size_t)(n_off + n0) * T_DIM;
  int frow = lane & 15;
  int fk = (lane >> 4) * 8;
  for (int k0 = 0; k0 < T_DIM; k0 += 32) {
    // stage: each wave-issue covers 16 rows (64 lanes x 16B = 1024B); lds dest = uniform base + lane*16
    #pragma unroll
    for (int it = 0; it < 2; it++) {
      int rbase = (it * 4 + wv) * 16;
      int row = rbase + (lane >> 2);
      int gcol = lane & 3;
      const bf16_t* gpa = Ag + (size_t)row * T_DIM + k0 + gcol * 8;
      const bf16_t* gpb = Bg + (size_t)row * T_DIM + k0 + gcol * 8;
      bf16_t* lpa = As + rbase * 32 + lane * 8;
      bf16_t* lpb = Bs + rbase * 32 + lane * 8;
      __builtin_amdgcn_global_load_lds(
          (const __attribute__((address_space(1))) void*)gpa,
          (__attribute__((address_space(3))) void*)lpa, 16, 0, 0);
      __builtin_amdgcn_global_load_lds(
          (const __attribute__((address_space(1))) void*)gpb,
          (__attribute__((address_space(3))) void*)lpb, 16, 0, 0);
    }
    __syncthreads();
    bf16x8 a[4], b[4];
    #pragma unroll
    for (int i = 0; i < 4; i++)
      a[i] = *(const bf16x8*)(As + (wm + i * 16 + frow) * 32 + fk);
    #pragma unroll
    for (int j = 0; j < 4; j++)
      b[j] = *(const bf16x8*)(Bs + (wn + j * 16 + frow) * 32 + fk);
    #pragma unroll
    for (int i = 0; i < 4; i++)
      #pragma unroll
      for (int j = 0; j < 4; j++)
        acc[i][j] = __builtin_amdgcn_mfma_f32_16x16x32_bf16(a[i], b[j], acc[i][j], 0, 0, 0);
    __syncthreads();
  }
  // C/D layout: row = (lane>>4)*4 + reg, col = lane&15  (m89/m91-verified)
  int col = lane & 15, qr = (lane >> 4) * 4;
  #pragma unroll
  for (int i = 0; i < 4; i++)
    #pragma unroll
    for (int j = 0; j < 4; j++) {
      int n = n0 + wn + j * 16 + col;
      #pragma unroll
      for (int r = 0; r < 4; r++) {
        int m = m0 + wm + i * 16 + qr + r;
        S[(size_t)m * C + n] = acc[i][j][r];
      }
    }
}

// ---------------- exact per-chunk top-128 via histogram pivot select ----------------
__global__ __launch_bounds__(256)
void select_kernel(const float* __restrict__ S, int C, int key_off,
                   int slot_off, int nslot,
                   float* __restrict__ cand_v, int* __restrict__ cand_i) {
  int q = blockIdx.x, tid = threadIdx.x;
  __shared__ unsigned hist[NBIN];
  __shared__ float bv[CAND_MAX];
  __shared__ int bi[CAND_MAX];
  __shared__ unsigned cnt_s, binB_s;
  for (int i = tid; i < NBIN; i += 256) hist[i] = 0;
  if (tid == 0) cnt_s = 0;
  __syncthreads();
  const float* row = S + (size_t)q * C;
  for (int i = tid; i < C; i += 256) {
    unsigned u = __float_as_uint(row[i]);
    u = (u & 0x80000000u) ? ~u : (u | 0x80000000u);
    atomicAdd(&hist[u >> 21], 1u);
  }
  __syncthreads();
  if (tid == 0) {
    unsigned acc = 0; unsigned B = 0;
    for (int b = NBIN - 1; b >= 0; b--) {
      acc += hist[b];
      if (acc >= (unsigned)K_KEEP) { B = (unsigned)b; break; }
    }
    binB_s = B;
  }
  __syncthreads();
  unsigned B = binB_s;
  for (int i = tid; i < C; i += 256) {
    float f = row[i];
    unsigned u = __float_as_uint(f);
    u = (u & 0x80000000u) ? ~u : (u | 0x80000000u);
    if ((u >> 21) >= B) {
      unsigned p = atomicAdd(&cnt_s, 1u);
      if (p < CAND_MAX) { bv[p] = f; bi[p] = key_off + i; }
    }
  }
  __syncthreads();
  int cnt = (int)min(cnt_s, (unsigned)CAND_MAX);
  int n = K_KEEP; while (n < cnt) n <<= 1;
  for (int x = cnt + tid; x < n; x += 256) { bv[x] = -FLT_MAX; bi[x] = 0x7FFFFFFF; }
  for (int k = 2; k <= n; k <<= 1) {
    for (int j = k >> 1; j > 0; j >>= 1) {
      __syncthreads();
      for (int i = tid; i < n; i += 256) {
        int ixj = i ^ j;
        if (ixj > i) {
          float a = bv[i], b = bv[ixj];
          int ia = bi[i], ib = bi[ixj];
          bool a_worse = (a < b) || (a == b && ia > ib);
          bool up = ((i & k) == 0);
          if (up ? a_worse : !a_worse) {
            bv[i] = b; bv[ixj] = a; bi[i] = ib; bi[ixj] = ia;
          }
        }
      }
    }
  }
  __syncthreads();
  if (tid < K_KEEP) {
    cand_v[(size_t)q * nslot + slot_off + tid] = bv[tid];
    cand_i[(size_t)q * nslot + slot_off + tid] = bi[tid];
  }
}

// ---------------- merge per-chunk candidate lists -> global top-128 indices ----------------
__global__ __launch_bounds__(256)
void merge_kernel(const float* __restrict__ cand_v, const int* __restrict__ cand_i,
                  int nslot, int* __restrict__ topi) {
  int q = blockIdx.x, tid = threadIdx.x;
  __shared__ float bv[CAND_MAX];
  __shared__ int bi[CAND_MAX];
  int n = K_KEEP; while (n < nslot) n <<= 1;
  for (int i = tid; i < n; i += 256) {
    if (i < nslot) { bv[i] = cand_v[(size_t)q * nslot + i]; bi[i] = cand_i[(size_t)q * nslot + i]; }
    else { bv[i] = -FLT_MAX; bi[i] = 0x7FFFFFFF; }
  }
  for (int k = 2; k <= n; k <<= 1) {
    for (int j = k >> 1; j > 0; j >>= 1) {
      __syncthreads();
      for (int i = tid; i < n; i += 256) {
        int ixj = i ^ j;
        if (ixj > i) {
          float a = bv[i], b = bv[ixj];
          int ia = bi[i], ib = bi[ixj];
          bool a_worse = (a < b) || (a == b && ia > ib);
          bool up = ((i & k) == 0);
          if (up ? a_worse : !a_worse) {
            bv[i] = b; bv[ixj] = a; bi[i] = ib; bi[ixj] = ia;
          }
        }
      }
    }
  }
  __syncthreads();
  if (tid < K_KEEP) topi[q * K_KEEP + tid] = bi[tid];
}

// ---------------- fp64 exact rescore + top-64 + softmax + gather + phase_norm ----------------
__global__ __launch_bounds__(256)
void rescore_kernel(const int* __restrict__ topi,
                    const double* __restrict__ Qd,
                    const double* __restrict__ qmagd, const double* __restrict__ kmagd,
                    const float* __restrict__ Kk, const float* __restrict__ V,
                    const float* __restrict__ gamma,
                    float* __restrict__ XN) {
  int q = blockIdx.x, tid = threadIdx.x;
  __shared__ double qrow[T_DIM];
  __shared__ double cval[K_KEEP];
  __shared__ int cidx[K_KEEP];
  __shared__ float w[K_TOP];
  __shared__ int widx[K_TOP];
  __shared__ float red[4];
  for (int i = tid; i < T_DIM; i += 256) qrow[i] = Qd[(size_t)q * T_DIM + i];
  if (tid < K_KEEP) cidx[tid] = topi[q * K_KEEP + tid];
  __syncthreads();
  double qm = qmagd[q];
  int wv = tid >> 6, ln = tid & 63;
  for (int c = wv; c < K_KEEP; c += 4) {
    int key = cidx[c];
    const float* kr = Kk + (size_t)key * T_DIM;
    double s = 0.0;
    #pragma unroll
    for (int it = 0; it < 16; it++) {
      int t = ln + it * 64;
      s += (double)kr[t] * qrow[t];
    }
    for (int o = 32; o > 0; o >>= 1) s += __shfl_down(s, o, 64);
    if (ln == 0) cval[c] = s / (qm * kmagd[key] + EPSD);
  }
  __syncthreads();
  for (int k = 2; k <= K_KEEP; k <<= 1) {
    for (int j = k >> 1; j > 0; j >>= 1) {
      __syncthreads();
      if (tid < K_KEEP) {
        int i = tid, ixj = i ^ j;
        if (ixj > i) {
          double a = cval[i], b = cval[ixj];
          int ia = cidx[i], ib = cidx[ixj];
          bool a_worse = (a < b) || (a == b && ia > ib);
          bool up = ((i & k) == 0);
          if (up ? a_worse : !a_worse) {
            cval[i] = b; cval[ixj] = a; cidx[i] = ib; cidx[ixj] = ia;
          }
        }
      }
    }
  }
  __syncthreads();
  if (tid < 64) {
    double v = cval[tid];
    double m = cval[0];
    double e = exp(v - m);
    double s = e;
    for (int o = 32; o > 0; o >>= 1) s += __shfl_down(s, o, 64);
    s = __shfl(s, 0, 64);
    w[tid] = (float)(e / s);
    widx[tid] = cidx[tid];
  }
  __syncthreads();
  float4 acc = {0.f, 0.f, 0.f, 0.f};
  #pragma unroll 4
  for (int j2 = 0; j2 < 64; j2++) {
    float wj = w[j2];
    float4 v = *(const float4*)(V + (size_t)widx[j2] * T_DIM + tid * 4);
    acc.x += wj * v.x; acc.y += wj * v.y; acc.z += wj * v.z; acc.w += wj * v.w;
  }
  float ls = acc.x*acc.x + acc.y*acc.y + acc.z*acc.z + acc.w*acc.w;
  for (int o = 32; o > 0; o >>= 1) ls += __shfl_down(ls, o, 64);
  if ((tid & 63) == 0) red[tid >> 6] = ls;
  __syncthreads();
  float tot = red[0] + red[1] + red[2] + red[3];
  float rms = sqrtf(tot / (float)D_DIM + EPSF);
  float g0 = gamma[tid * 2] / rms, g1 = gamma[tid * 2 + 1] / rms;
  float4 o = { acc.x * g0, acc.y * g0, acc.z * g1, acc.w * g1 };
  *(float4*)(XN + (size_t)q * T_DIM + tid * 4) = o;
}

extern "C" void kernel_launch(void* const* d_in, const int* in_sizes, int n_in,
                              void* d_out, int out_size, void* d_ws, size_t ws_size,
                              hipStream_t stream) {
  const float* query  = (const float*)d_in[0];
  const float* keys   = (const float*)d_in[1];
  const float* values = (const float*)d_in[2];
  const float* Wq_r   = (const float*)d_in[3];
  const float* Wq_i   = (const float*)d_in[4];
  const float* bq_r   = (const float*)d_in[5];
  const float* bq_i   = (const float*)d_in[6];
  const float* Wo_r   = (const float*)d_in[7];
  const float* Wo_i   = (const float*)d_in[8];
  const float* bo_r   = (const float*)d_in[9];
  const float* bo_i   = (const float*)d_in[10];
  const float* gamma  = (const float*)d_in[11];
  float* out = (float*)d_out;

  int M = in_sizes[0] / T_DIM;   // 4096
  int N = in_sizes[1] / T_DIM;   // 32768

  char* ws = (char*)d_ws;
  size_t off = 0;
  double* qd    = (double*)(ws + off); off += (size_t)M * T_DIM * 8;
  float*  xn    = (float*) (ws + off); off += (size_t)M * T_DIM * 4;
  double* qmagd = (double*)(ws + off); off += (size_t)M * 8;
  double* kmagd = (double*)(ws + off); off += (size_t)N * 8;
  int*    topi  = (int*)   (ws + off); off += (size_t)M * K_KEEP * 4;
  float*  candv = (float*) (ws + off); off += (size_t)M * CAND_MAX * 4;
  int*    candi = (int*)   (ws + off); off += (size_t)M * CAND_MAX * 4;
  bf16_t* qn    = (bf16_t*)(ws + off); off += (size_t)M * T_DIM * 2;
  bf16_t* kn    = (bf16_t*)(ws + off); off += (size_t)N * T_DIM * 2;
  float*  sc    = (float*) (ws + off);
  size_t remain = (ws_size > off) ? (ws_size - off) : 0;

  int C = 2048;
  for (int c = 32768; c >= 2048; c >>= 1) {
    if (c <= N && (size_t)M * c * 4 <= remain) { C = c; break; }
  }
  if (C > N) C = N;
  int nchunks = N / C;
  int nslot = nchunks * K_KEEP;   // <= 2048

  dim3 blk(256);
  cgemm_f64_kernel<<<dim3(M / 64, D_DIM / 64), blk, 0, stream>>>(query, Wq_r, Wq_i, bq_r, bq_i, qd, M);
  rownorm_convert_q_kernel<<<dim3(M), blk, 0, stream>>>(qd, qmagd, qn, M);
  rownorm_convert_k_kernel<<<dim3(N), blk, 0, stream>>>(keys, kmagd, kn, N);
  for (int c = 0; c < nchunks; c++) {
    int noff = c * C;
    mfma_score_kernel<<<dim3(M / 128, C / 128), blk, 0, stream>>>(qn, kn, sc, noff, C);
    select_kernel<<<dim3(M), blk, 0, stream>>>(sc, C, noff, c * K_KEEP, nslot, candv, candi);
  }
  merge_kernel<<<dim3(M), blk, 0, stream>>>(candv, candi, nslot, topi);
  rescore_kernel<<<dim3(M), blk, 0, stream>>>(topi, qd, qmagd, kmagd, keys, values, gamma, xn);
  cgemm_kernel<<<dim3(M / 64, D_DIM / 64), blk, 0, stream>>>(xn, Wo_r, Wo_i, bo_r, bo_i, out, M);
}